// Round 1
// baseline (122542.188 us; speedup 1.0000x reference)
//
#include <hip/hip_runtime.h>
#include <hip/hip_cooperative_groups.h>
#include <math.h>

namespace cg = cooperative_groups;

#define H      1024
#define LBLP1  33      // LABEL_SIZE + 1
#define NE     4096
#define NS     4096
#define NSTEP  (NE - 1)   // 4095 scan steps
#define TGT    1
#define NWG    256
#define UPW    4          // hidden units per workgroup
#define ROWS   28         // 7 gates * UPW
#define SCAN_THREADS 512

__device__ __forceinline__ float wave_sum(float v) {
#pragma unroll
    for (int o = 32; o > 0; o >>= 1) v += __shfl_xor(v, o, 64);
    return v;
}

__device__ __forceinline__ float softplusf(float x) {
    return x > 0.f ? x + log1pf(expf(-x)) : log1pf(expf(x));
}
__device__ __forceinline__ float sigmoidf(float x) {
    return 1.f / (1.f + expf(-x));
}

// WEmb[e][h][l] = sum_k W[e][h][k] * Emb[k][l] + d[e][h]
__global__ void wemb_kernel(const float* __restrict__ W, const float* __restrict__ Emb,
                            const float* __restrict__ dbias, float* __restrict__ WEmb) {
    int row = blockIdx.x;  // e*H + h, 0..7*H-1
    __shared__ float wrow[H];
    for (int i = threadIdx.x; i < H; i += blockDim.x) wrow[i] = W[(size_t)row * H + i];
    __syncthreads();
    int l = threadIdx.x;
    if (l < LBLP1) {
        float a = dbias[row];
        for (int k = 0; k < H; ++k) a += wrow[k] * Emb[k * LBLP1 + l];
        WEmb[row * LBLP1 + l] = a;
    }
}

// Persistent cooperative scan. 256 WGs, each owns 4 hidden units for all 7 gates.
__global__ __launch_bounds__(SCAN_THREADS)
void scan_kernel(const float* __restrict__ WEmb, const float* __restrict__ U,
                 const int* __restrict__ label_seq, const float* __restrict__ time_seq,
                 float* __restrict__ hbuf, float* __restrict__ all_h, float* __restrict__ all_o,
                 float* __restrict__ all_cb, float* __restrict__ all_cc, float* __restrict__ all_dl) {
    cg::grid_group grid = cg::this_grid();
    const int tid  = threadIdx.x;
    const int wg   = blockIdx.x;
    const int wave = tid >> 6;
    const int lane = tid & 63;

    extern __shared__ float smem[];
    float* Uld     = smem;               // ROWS * H
    float* h_sh    = Uld + ROWS * H;     // H
    float* temp_sh = h_sh + H;           // ROWS
    float* act_sh  = temp_sh + ROWS;     // ROWS

    // Load this WG's 28 rows of U into LDS (one time).
    for (int idx = tid; idx < ROWS * H; idx += SCAN_THREADS) {
        int r = idx >> 10, k = idx & (H - 1);
        int e = r >> 2, j = r & 3;
        int u = wg * UPW + j;
        Uld[idx] = U[((size_t)e * H + u) * H + k];
    }
    // init h_0 = 0
    if (tid < UPW) hbuf[wg * UPW + tid] = 0.f;
    float c_t = 0.f, cbar = 0.f;

    for (int t = 0; t < NSTEP; ++t) {
        grid.sync();  // h_t fully written & visible device-wide

        const float* hin = hbuf + (t & 1) * H;
        for (int i = tid; i < H; i += SCAN_THREADS) h_sh[i] = hin[i];
        __syncthreads();

        // 28 dot products of length 1024 against LDS-resident U rows
        for (int r = wave; r < ROWS; r += (SCAN_THREADS / 64)) {
            const float* urow = &Uld[r << 10];
            float a = 0.f;
#pragma unroll
            for (int m = 0; m < 16; ++m) {
                int i = lane + (m << 6);
                a += urow[i] * h_sh[i];
            }
            a = wave_sum(a);
            if (lane == 0) temp_sh[r] = a;
        }
        __syncthreads();

        // activations, one thread per (gate, unit)
        if (tid < ROWS) {
            int e = tid >> 2, j = tid & 3;
            int u = wg * UPW + j;
            int lab = label_seq[t];
            float g = WEmb[((size_t)e * H + u) * LBLP1 + lab] + temp_sh[tid];
            float a;
            if (e == 2)      a = tanhf(g);
            else if (e == 6) a = softplusf(g);
            else             a = sigmoidf(g);
            act_sh[tid] = a;
        }
        __syncthreads();

        // state update, one thread per unit
        if (tid < UPW) {
            float i_g = act_sh[0  + tid];
            float f_g = act_sh[4  + tid];
            float z   = act_sh[8  + tid];
            float o   = act_sh[12 + tid];
            float i_b = act_sh[16 + tid];
            float f_b = act_sh[20 + tid];
            float dl  = act_sh[24 + tid];
            float dt  = time_seq[t + 1] - time_seq[t];
            float c   = f_g * c_t + i_g * z;
            float cbn = f_b * cbar + i_b * z;
            float ctn = cbn + (c - cbn) * expf(-dl * dt);
            float hn  = o * tanhf(ctn);
            c_t = ctn; cbar = cbn;
            int u = wg * UPW + tid;
            hbuf[((t + 1) & 1) * H + u] = hn;
            size_t p = (size_t)t * H + u;
            all_h [p] = hn;
            all_o [p] = o;
            all_cb[p] = cbn;
            all_cc[p] = c;
            all_dl[p] = dl;
        }
        // next grid.sync() provides the block-level barrier too
    }
}

__global__ void term1_kernel(const float* __restrict__ all_h, const int* __restrict__ label_seq,
                             const float* __restrict__ w, const float* __restrict__ log_s,
                             const int* __restrict__ ignore_first, float* __restrict__ acc) {
    int beg = (*ignore_first) ? 1 : 0;
    int j = blockIdx.x;
    if (j >= (NSTEP - 1 - beg)) return;           // h_evt count = 4094 - beg
    if (label_seq[1 + beg + j] != TGT) return;
    const float* hrow = all_h + (size_t)(beg + j) * H;
    const float* w0 = w + (TGT - 1) * H;
    float part = 0.f;
    for (int i = threadIdx.x; i < H; i += blockDim.x) part += hrow[i] * w0[i];
    __shared__ float red[4];
    part = wave_sum(part);
    if ((threadIdx.x & 63) == 0) red[threadIdx.x >> 6] = part;
    __syncthreads();
    if (threadIdx.x == 0) {
        float tot = red[0] + red[1] + red[2] + red[3];
        float s0 = expf(log_s[TGT - 1]);
        float lam = s0 * softplusf(tot / s0) + 1e-9f;
        atomicAdd(acc, logf(lam));
    }
}

__global__ void term2_kernel(const float* __restrict__ all_o, const float* __restrict__ all_cb,
                             const float* __restrict__ all_cc, const float* __restrict__ all_dl,
                             const int* __restrict__ sim_idx, const float* __restrict__ sim_time,
                             const float* __restrict__ time_seq, const float* __restrict__ w,
                             const float* __restrict__ log_s, float* __restrict__ acc) {
    int i = blockIdx.x;
    int idx = sim_idx[i];
    float dtp = sim_time[i] - time_seq[idx];
    size_t base = (size_t)idx * H;
    const float* w0 = w + (TGT - 1) * H;
    float part = 0.f;
    for (int hh = threadIdx.x; hh < H; hh += blockDim.x) {
        float cb = all_cb[base + hh];
        float cc = all_cc[base + hh];
        float dl = all_dl[base + hh];
        float oo = all_o [base + hh];
        float cs = cb + (cc - cb) * expf(-dl * dtp);
        part += oo * tanhf(cs) * w0[hh];
    }
    __shared__ float red[4];
    part = wave_sum(part);
    if ((threadIdx.x & 63) == 0) red[threadIdx.x >> 6] = part;
    __syncthreads();
    if (threadIdx.x == 0) {
        float tot = red[0] + red[1] + red[2] + red[3];
        float s0 = expf(log_s[TGT - 1]);
        float lam = s0 * softplusf(tot / s0) + 1e-9f;
        atomicAdd(acc + 1, lam);
    }
}

__global__ void finish_kernel(const float* __restrict__ acc, const float* __restrict__ time_seq,
                              float* __restrict__ out) {
    float T = time_seq[NE - 1] - time_seq[0];
    out[0] = -(acc[0] - acc[1] * (T / (float)NS));
}

extern "C" void kernel_launch(void* const* d_in, const int* in_sizes, int n_in,
                              void* d_out, int out_size, void* d_ws, size_t ws_size,
                              hipStream_t stream) {
    const int*   label_seq    = (const int*)  d_in[0];
    const float* time_seq     = (const float*)d_in[1];
    const float* sim_time     = (const float*)d_in[2];
    const int*   sim_idx      = (const int*)  d_in[3];
    const int*   ignore_first = (const int*)  d_in[4];
    const float* Emb   = (const float*)d_in[5];
    const float* W     = (const float*)d_in[6];
    const float* U     = (const float*)d_in[7];
    const float* dbias = (const float*)d_in[8];
    const float* w     = (const float*)d_in[9];
    const float* log_s = (const float*)d_in[10];
    float* out = (float*)d_out;

    float* ws = (float*)d_ws;
    size_t off = 0;
    float* WEmb   = ws + off; off += 7 * H * LBLP1;
    float* hbuf   = ws + off; off += 2 * H;
    float* all_h  = ws + off; off += (size_t)NSTEP * H;
    float* all_o  = ws + off; off += (size_t)NSTEP * H;
    float* all_cb = ws + off; off += (size_t)NSTEP * H;
    float* all_cc = ws + off; off += (size_t)NSTEP * H;
    float* all_dl = ws + off; off += (size_t)NSTEP * H;
    float* acc    = ws + off; off += 2;

    hipMemsetAsync(acc, 0, 2 * sizeof(float), stream);

    hipLaunchKernelGGL(wemb_kernel, dim3(7 * H), dim3(64), 0, stream, W, Emb, dbias, WEmb);

    // dynamic LDS: 28 rows of U + h + temp + act
    unsigned int smem_bytes = (unsigned int)((ROWS * H + H + ROWS + ROWS) * sizeof(float));
    hipFuncSetAttribute((const void*)scan_kernel, hipFuncAttributeMaxDynamicSharedMemorySize,
                        (int)smem_bytes);
    void* args[] = { (void*)&WEmb, (void*)&U, (void*)&label_seq, (void*)&time_seq,
                     (void*)&hbuf, (void*)&all_h, (void*)&all_o, (void*)&all_cb,
                     (void*)&all_cc, (void*)&all_dl };
    hipLaunchCooperativeKernel((void*)scan_kernel, dim3(NWG), dim3(SCAN_THREADS),
                               args, smem_bytes, stream);

    hipLaunchKernelGGL(term1_kernel, dim3(NSTEP - 1), dim3(256), 0, stream,
                       all_h, label_seq, w, log_s, ignore_first, acc);
    hipLaunchKernelGGL(term2_kernel, dim3(NS), dim3(256), 0, stream,
                       all_o, all_cb, all_cc, all_dl, sim_idx, sim_time, time_seq, w, log_s, acc);
    hipLaunchKernelGGL(finish_kernel, dim3(1), dim3(1), 0, stream, acc, time_seq, out);
}

// Round 2
// 19631.941 us; speedup vs baseline: 6.2420x; 6.2420x over previous
//
#include <hip/hip_runtime.h>
#include <math.h>

#define H      1024
#define LBLP1  33        // LABEL_SIZE + 1
#define NE     4096
#define NS     4096
#define NSTEP  (NE - 1)  // 4095 scan steps
#define TGT    1
#define NWG    256
#define UPW    4         // hidden units per workgroup
#define ROWS   28        // 7 gates * UPW
#define SCAN_THREADS 512
#define LEAF_GROUPS 16   // 16 groups of 16 WGs
#define ROOT_OFF (LEAF_GROUPS * 32)
#define FLAG_OFF (ROOT_OFF + 32)
#define BAR_UINTS 1024

__device__ __forceinline__ float wave_sum(float v) {
#pragma unroll
    for (int o = 32; o > 0; o >>= 1) v += __shfl_xor(v, o, 64);
    return v;
}

__device__ __forceinline__ float softplusf(float x) {
    return x > 0.f ? x + log1pf(expf(-x)) : log1pf(expf(x));
}
__device__ __forceinline__ float sigmoidf(float x) {
    return 1.f / (1.f + expf(-x));
}

// WEmb[(e*H+h)*33 + l] = sum_k W[e][h][k] * Emb[k][l] + d[e][h]
// One wave per (row, l) dot.
__global__ void wemb_kernel(const float* __restrict__ W, const float* __restrict__ Emb,
                            const float* __restrict__ dbias, float* __restrict__ WEmb) {
    int gw   = blockIdx.x * (blockDim.x >> 6) + (threadIdx.x >> 6);
    int lane = threadIdx.x & 63;
    if (gw >= 7 * H * LBLP1) return;
    int row = gw / LBLP1;
    int l   = gw - row * LBLP1;
    const float* wrow = W + (size_t)row * H;
    float a = 0.f;
#pragma unroll
    for (int m = 0; m < 16; ++m) {
        int k = lane + (m << 6);
        a = fmaf(wrow[k], Emb[k * LBLP1 + l], a);
    }
    a = wave_sum(a);
    if (lane == 0) WEmb[(size_t)row * LBLP1 + l] = a + dbias[row];
}

// Persistent scan: 256 WGs, each owns 4 hidden units across all 7 gates.
// Custom 2-level tree barrier; h exchanged via agent-scope write-through atomics.
__global__ __launch_bounds__(SCAN_THREADS)
void scan_kernel(const float* __restrict__ WEmb, const float* __restrict__ U,
                 const int* __restrict__ label_seq, const float* __restrict__ time_seq,
                 float* __restrict__ hbuf, unsigned* __restrict__ bar,
                 float* __restrict__ all_h, float* __restrict__ all_o,
                 float* __restrict__ all_cb, float* __restrict__ all_cc,
                 float* __restrict__ all_dl) {
    const int tid  = threadIdx.x;
    const int wg   = blockIdx.x;
    const int wave = tid >> 6;
    const int lane = tid & 63;

    extern __shared__ float smem[];
    float* Uld    = smem;             // ROWS * H
    float* h_sh   = Uld + ROWS * H;   // H
    float* act_sh = h_sh + H;         // ROWS

    // Stage this WG's 28 rows of U into LDS (once). Coalesced over k.
    for (int idx = tid; idx < ROWS * H; idx += SCAN_THREADS) {
        int r = idx >> 10, k = idx & (H - 1);
        int e = r >> 2, j = r & 3;
        Uld[idx] = U[((size_t)e * H + (wg * UPW + j)) * H + k];
    }

    float c_t = 0.f, cbar = 0.f;
    const float4* h4 = (const float4*)h_sh;

    for (int t = 0; t < NSTEP; ++t) {
        // --- issue independent loads early ---
        const int lab = label_seq[t];                     // uniform
        const float dt = time_seq[t + 1] - time_seq[t];   // uniform

        unsigned long long hv = 0ull;
        if (t > 0) {
            const unsigned long long* hin =
                (const unsigned long long*)(hbuf + (t & 1) * H);
            hv = __hip_atomic_load(hin + tid, __ATOMIC_RELAXED,
                                   __HIP_MEMORY_SCOPE_AGENT);
        }
        float gb[4];
#pragma unroll
        for (int i = 0; i < 4; ++i) {
            int r = wave + (i << 3);
            if (r < ROWS) {
                int e = r >> 2, j = r & 3;
                gb[i] = WEmb[((size_t)e * H + (wg * UPW + j)) * LBLP1 + lab];
            } else gb[i] = 0.f;
        }

        // --- h broadcast into LDS ---
        {
            union { unsigned long long u; float f[2]; } cv; cv.u = hv;
            h_sh[2 * tid]     = cv.f[0];
            h_sh[2 * tid + 1] = cv.f[1];
        }
        __syncthreads();

        // --- 28 LDS float4 dots; activation fused on lane 0 ---
#pragma unroll
        for (int i = 0; i < 4; ++i) {
            int r = wave + (i << 3);
            if (r < ROWS) {
                const float4* u4 = (const float4*)(Uld + (r << 10));
                float a = 0.f;
#pragma unroll
                for (int m = 0; m < 4; ++m) {
                    float4 u  = u4[(m << 6) + lane];
                    float4 hh = h4[(m << 6) + lane];
                    a = fmaf(u.x, hh.x, a); a = fmaf(u.y, hh.y, a);
                    a = fmaf(u.z, hh.z, a); a = fmaf(u.w, hh.w, a);
                }
                a = wave_sum(a);
                if (lane == 0) {
                    float g = gb[i] + a;
                    int e = r >> 2;
                    float act;
                    if (e == 2)      act = tanhf(g);
                    else if (e == 6) act = softplusf(g);
                    else             act = sigmoidf(g);
                    act_sh[r] = act;
                }
            }
        }
        __syncthreads();

        // --- state update (4 threads, same wave as the barrier thread) ---
        if (tid < UPW) {
            float i_g = act_sh[tid],      f_g = act_sh[4 + tid];
            float z   = act_sh[8 + tid],  o   = act_sh[12 + tid];
            float i_b = act_sh[16 + tid], f_b = act_sh[20 + tid];
            float dl  = act_sh[24 + tid];
            float c   = fmaf(f_g, c_t, i_g * z);
            float cbn = fmaf(f_b, cbar, i_b * z);
            float ctn = cbn + (c - cbn) * expf(-dl * dt);
            float hn  = o * tanhf(ctn);
            c_t = ctn; cbar = cbn;
            int u = wg * UPW + tid;
            float* hb_out = hbuf + ((t + 1) & 1) * H;
            __hip_atomic_store(&hb_out[u], hn, __ATOMIC_RELAXED,
                               __HIP_MEMORY_SCOPE_AGENT);
            size_t p = (size_t)t * H + u;
            all_h [p] = hn;
            all_o [p] = o;
            all_cb[p] = cbn;
            all_cc[p] = c;
            all_dl[p] = dl;
        }

        // --- tree barrier (skip after the final step) ---
        if (t + 1 < NSTEP) {
            if (tid == 0) {
                __threadfence_block();  // s_waitcnt vmcnt(0): h stores complete
                unsigned old = atomicAdd(&bar[(wg >> 4) * 32], 1u);
                if ((old & 15u) == 15u) {
                    unsigned rold = atomicAdd(&bar[ROOT_OFF], 1u);
                    if ((rold & 15u) == 15u) {
                        __hip_atomic_store(&bar[FLAG_OFF], (unsigned)(t + 1),
                                           __ATOMIC_RELAXED, __HIP_MEMORY_SCOPE_AGENT);
                    }
                }
                while (__hip_atomic_load(&bar[FLAG_OFF], __ATOMIC_RELAXED,
                                         __HIP_MEMORY_SCOPE_AGENT) < (unsigned)(t + 1)) {
                    __builtin_amdgcn_s_sleep(1);
                }
            }
            __syncthreads();
        }
    }
}

__global__ void term1_kernel(const float* __restrict__ all_h, const int* __restrict__ label_seq,
                             const float* __restrict__ w, const float* __restrict__ log_s,
                             const int* __restrict__ ignore_first, float* __restrict__ acc) {
    int beg = (*ignore_first) ? 1 : 0;
    int j = blockIdx.x;
    if (j >= (NSTEP - 1 - beg)) return;
    if (label_seq[1 + beg + j] != TGT) return;
    const float* hrow = all_h + (size_t)(beg + j) * H;
    const float* w0 = w + (TGT - 1) * H;
    float part = 0.f;
    for (int i = threadIdx.x; i < H; i += blockDim.x) part += hrow[i] * w0[i];
    __shared__ float red[4];
    part = wave_sum(part);
    if ((threadIdx.x & 63) == 0) red[threadIdx.x >> 6] = part;
    __syncthreads();
    if (threadIdx.x == 0) {
        float tot = red[0] + red[1] + red[2] + red[3];
        float s0 = expf(log_s[TGT - 1]);
        float lam = s0 * softplusf(tot / s0) + 1e-9f;
        atomicAdd(acc, logf(lam));
    }
}

__global__ void term2_kernel(const float* __restrict__ all_o, const float* __restrict__ all_cb,
                             const float* __restrict__ all_cc, const float* __restrict__ all_dl,
                             const int* __restrict__ sim_idx, const float* __restrict__ sim_time,
                             const float* __restrict__ time_seq, const float* __restrict__ w,
                             const float* __restrict__ log_s, float* __restrict__ acc) {
    int i = blockIdx.x;
    int idx = sim_idx[i];
    float dtp = sim_time[i] - time_seq[idx];
    size_t base = (size_t)idx * H;
    const float* w0 = w + (TGT - 1) * H;
    float part = 0.f;
    for (int hh = threadIdx.x; hh < H; hh += blockDim.x) {
        float cb = all_cb[base + hh];
        float cc = all_cc[base + hh];
        float dl = all_dl[base + hh];
        float oo = all_o [base + hh];
        float cs = cb + (cc - cb) * expf(-dl * dtp);
        part += oo * tanhf(cs) * w0[hh];
    }
    __shared__ float red[4];
    part = wave_sum(part);
    if ((threadIdx.x & 63) == 0) red[threadIdx.x >> 6] = part;
    __syncthreads();
    if (threadIdx.x == 0) {
        float tot = red[0] + red[1] + red[2] + red[3];
        float s0 = expf(log_s[TGT - 1]);
        float lam = s0 * softplusf(tot / s0) + 1e-9f;
        atomicAdd(acc + 1, lam);
    }
}

__global__ void finish_kernel(const float* __restrict__ acc, const float* __restrict__ time_seq,
                              float* __restrict__ out) {
    float T = time_seq[NE - 1] - time_seq[0];
    out[0] = -(acc[0] - acc[1] * (T / (float)NS));
}

extern "C" void kernel_launch(void* const* d_in, const int* in_sizes, int n_in,
                              void* d_out, int out_size, void* d_ws, size_t ws_size,
                              hipStream_t stream) {
    const int*   label_seq    = (const int*)  d_in[0];
    const float* time_seq     = (const float*)d_in[1];
    const float* sim_time     = (const float*)d_in[2];
    const int*   sim_idx      = (const int*)  d_in[3];
    const int*   ignore_first = (const int*)  d_in[4];
    const float* Emb   = (const float*)d_in[5];
    const float* W     = (const float*)d_in[6];
    const float* U     = (const float*)d_in[7];
    const float* dbias = (const float*)d_in[8];
    const float* w     = (const float*)d_in[9];
    const float* log_s = (const float*)d_in[10];
    float* out = (float*)d_out;

    float* ws = (float*)d_ws;
    size_t off = 0;
    unsigned* bar = (unsigned*)ws;  off += BAR_UINTS;        // barrier state (zeroed per launch)
    float* acc    = ws + off;       off += 32;               // [0]=term1, [1]=term2-sum
    float* WEmb   = ws + off;       off += 7 * H * LBLP1;
    off = (off + 3) & ~(size_t)3;                            // 16B align
    float* hbuf   = ws + off;       off += 2 * H;
    float* all_h  = ws + off;       off += (size_t)NSTEP * H;
    float* all_o  = ws + off;       off += (size_t)NSTEP * H;
    float* all_cb = ws + off;       off += (size_t)NSTEP * H;
    float* all_cc = ws + off;       off += (size_t)NSTEP * H;
    float* all_dl = ws + off;       off += (size_t)NSTEP * H;

    hipMemsetAsync(bar, 0, BAR_UINTS * sizeof(unsigned), stream);
    hipMemsetAsync(acc, 0, 2 * sizeof(float), stream);

    {
        int total_waves = 7 * H * LBLP1;
        int blocks = (total_waves + 3) / 4;
        hipLaunchKernelGGL(wemb_kernel, dim3(blocks), dim3(256), 0, stream,
                           W, Emb, dbias, WEmb);
    }

    unsigned int smem_bytes = (unsigned int)((ROWS * H + H + ROWS) * sizeof(float));
    hipFuncSetAttribute((const void*)scan_kernel, hipFuncAttributeMaxDynamicSharedMemorySize,
                        (int)smem_bytes);
    void* args[] = { (void*)&WEmb, (void*)&U, (void*)&label_seq, (void*)&time_seq,
                     (void*)&hbuf, (void*)&bar, (void*)&all_h, (void*)&all_o,
                     (void*)&all_cb, (void*)&all_cc, (void*)&all_dl };
    hipLaunchCooperativeKernel((void*)scan_kernel, dim3(NWG), dim3(SCAN_THREADS),
                               args, smem_bytes, stream);

    hipLaunchKernelGGL(term1_kernel, dim3(NSTEP - 1), dim3(256), 0, stream,
                       all_h, label_seq, w, log_s, ignore_first, acc);
    hipLaunchKernelGGL(term2_kernel, dim3(NS), dim3(256), 0, stream,
                       all_o, all_cb, all_cc, all_dl, sim_idx, sim_time, time_seq, w, log_s, acc);
    hipLaunchKernelGGL(finish_kernel, dim3(1), dim3(1), 0, stream, acc, time_seq, out);
}